// Round 4
// baseline (1204.562 us; speedup 1.0000x reference)
//
#include <hip/hip_runtime.h>
#include <hip/hip_bf16.h>
#include <cmath>
#include <complex>

#define TPB 256
#define WPB 4          // waves per block (1 dst node per wave)
#define NM 115
#define NW3J 363
#define SCAN_T 1024

typedef __attribute__((ext_vector_type(8))) short bf16x8;
typedef __attribute__((ext_vector_type(4))) float f32x4;

// ---------------- host-side W3J construction (exact port of reference) ------
namespace {

double fct(int n){ double r=1; for(int i=2;i<=n;i++) r*=i; return r; }

double su2_cg(int j1,int j2,int j3,int m1,int m2,int m3){
  if(m1+m2!=m3) return 0.0;
  double pref = std::sqrt((2*j3+1)*fct(j1+j2-j3)*fct(j1-j2+j3)*fct(-j1+j2+j3)/fct(j1+j2+j3+1));
  pref *= std::sqrt(fct(j3+m3)*fct(j3-m3)*fct(j1-m1)*fct(j1+m1)*fct(j2-m2)*fct(j2+m2));
  double s=0;
  for(int k=0;k<=j1+j2-j3;k++){
    int d0=k, d1=j1+j2-j3-k, d2=j1-m1-k, d3=j2+m2-k, d4=j3-j2+m1+k, d5=j3-j1-m2+k;
    if(d0<0||d1<0||d2<0||d3<0||d4<0||d5<0) continue;
    double t = 1.0/(fct(d0)*fct(d1)*fct(d2)*fct(d3)*fct(d4)*fct(d5));
    s += (k&1)? -t : t;
  }
  return pref*s;
}

typedef std::complex<double> cd;

void qmat(int l, cd q[5][5]){
  for(int i=0;i<5;i++) for(int j=0;j<5;j++) q[i][j] = cd(0,0);
  const double is2 = 1.0/std::sqrt(2.0);
  for(int m=-l;m<0;m++){ q[l+m][l-m] = cd(is2,0); q[l+m][l+m] = cd(0,-is2); }
  q[l][l] = cd(1,0);
  for(int m=1;m<=l;m++){ double sg = (m&1)? -1.0: 1.0; q[l+m][l+m] = cd(sg*is2,0); q[l+m][l-m] = cd(0, sg*is2); }
  cd ph(1,0), mi(0,-1);
  for(int t=0;t<l;t++) ph *= mi;
  for(int i=0;i<5;i++) for(int j=0;j<5;j++) q[i][j] *= ph;
}

void w3j_calc(int l1,int l2,int l3,double* out){
  int n1=2*l1+1,n2=2*l2+1,n3=2*l3+1;
  double C[5][5][5] = {};
  for(int m1=-l1;m1<=l1;m1++)for(int m2=-l2;m2<=l2;m2++)for(int m3=-l3;m3<=l3;m3++)
    C[l1+m1][l2+m2][l3+m3] = su2_cg(l1,l2,l3,m1,m2,m3);
  cd q1[5][5], q2[5][5], q3[5][5];
  qmat(l1,q1); qmat(l2,q2); qmat(l3,q3);
  double wr[125], wi[125];
  double nr=0, ni=0;
  for(int a=0;a<n1;a++)for(int b=0;b<n2;b++)for(int c=0;c<n3;c++){
    cd s(0,0);
    for(int i=0;i<n1;i++)for(int k=0;k<n2;k++)for(int m=0;m<n3;m++)
      s += q1[i][a]*q2[k][b]*std::conj(q3[m][c])*C[i][k][m];
    int idx = (a*n2+b)*n3+c;
    wr[idx]=s.real(); wi[idx]=s.imag();
    nr += s.real()*s.real(); ni += s.imag()*s.imag();
  }
  bool useR = std::sqrt(nr) >= std::sqrt(ni);
  double nn = std::sqrt(useR? nr: ni);
  for(int q=0;q<n1*n2*n3;q++) out[q] = (useR? wr[q]: wi[q])/nn;
}

struct UploadArg {
  float w3j[NW3J];        // PATH_W premultiplied, dense per path
  unsigned int meta[NM];  // per M-entry: woff | nc<<10 | nb<<14 | boff<<18
};

UploadArg g_upload;

struct BuildInit {
  BuildInit(){
    const int P[11][3] = {{0,0,0},{0,1,1},{0,2,2},{1,0,1},{1,1,0},{1,1,2},
                          {1,2,1},{2,0,2},{2,1,1},{2,2,0},{2,2,2}};
    const int cnt[3] = {3,4,4};
    const int AO[3] = {0,1,4};
    int off = 0, t = 0;
    for(int p=0;p<11;p++){
      int i=P[p][0], j=P[p][1], k=P[p][2];
      int na=2*i+1, nb=2*j+1, nc=2*k+1;
      double W[125];
      w3j_calc(i,j,k,W);
      double pw = std::sqrt((2.0*k+1.0)/(double)cnt[k]);
      for(int q=0;q<na*nb*nc;q++) g_upload.w3j[off+q] = (float)(W[q]*pw);
      for(int a=0;a<na;a++)
        for(int c=0;c<nc;c++)
          g_upload.meta[t++] = (unsigned)((off + a*nb*nc + c) | (nc<<10) | (nb<<14) | (AO[j]<<18));
      off += na*nb*nc;
    }
  }
};
BuildInit g_build_init;

} // namespace

// ---------------- CSR build kernels ----------------------------------------

__global__ void count_kernel(const int* __restrict__ dst, int* __restrict__ counts, int E){
  int e = blockIdx.x*blockDim.x + threadIdx.x;
  if(e < E) atomicAdd(&counts[dst[e]], 1);
}

__global__ __launch_bounds__(SCAN_T) void scan_kernel(const int* __restrict__ counts,
                                                      int* __restrict__ off,
                                                      int* __restrict__ cursor, int NN){
  __shared__ int part[SCAN_T];
  int t = threadIdx.x;
  int C = (NN + SCAN_T - 1)/SCAN_T;
  int base = t*C;
  int lim = min(base+C, NN);
  int s = 0;
  for(int i=base;i<lim;i++) s += counts[i];
  part[t] = s;
  __syncthreads();
  for(int d=1; d<SCAN_T; d<<=1){
    int v = (t>=d)? part[t-d] : 0;
    __syncthreads();
    part[t] += v;
    __syncthreads();
  }
  int run = part[t] - s;
  for(int i=base;i<lim;i++){ off[i]=run; cursor[i]=run; run += counts[i]; }
  if(t == SCAN_T-1) off[NN] = part[t];
}

__global__ void edge_scatter_kernel(const int* __restrict__ dst, int* __restrict__ cursor,
                                    int* __restrict__ eid, int E){
  int e = blockIdx.x*blockDim.x + threadIdx.x;
  if(e < E){
    int p = atomicAdd(&cursor[dst[e]], 1);
    eid[p] = e;
  }
}

// repack w2 [64][352] f32 -> bf16 B-fragment order for mfma_f32_16x16x32_bf16
__global__ void repack_w2f(const float* __restrict__ w2, unsigned short* __restrict__ w2f){
  int t_ = blockIdx.x*blockDim.x + threadIdx.x;
  if(t_ >= 22*2*64*8) return;
  int jj = t_ & 7;
  int lane = (t_>>3) & 63;
  int kk = (t_>>9) & 1;
  int t  = t_>>10;
  int n = t*16 + (lane & 15);
  int k = kk*32 + ((lane>>4)&3)*8 + jj;
  unsigned ub = __float_as_uint(w2[k*352 + n]);
  ub = (ub + 0x7fffu + ((ub>>16)&1u)) >> 16;   // RNE to bf16
  w2f[t_] = (unsigned short)ub;
}

// ---------------- main node-owned MFMA kernel -------------------------------

__global__ __launch_bounds__(TPB) void node_kernel(
    const float* __restrict__ nodes,
    const float* __restrict__ pos,
    const int* __restrict__ src,
    const int* __restrict__ offp,
    const int* __restrict__ eid,
    const unsigned short* __restrict__ w2f,
    const float* __restrict__ w1,
    const float* __restrict__ b1,
    const float* __restrict__ b2,
    float* __restrict__ outp,
    int NN, UploadArg up)
{
  __shared__ float s_w3j[NW3J];
  __shared__ float s_b2[352];
  __shared__ float s_w1[512];
  __shared__ float s_b1[64];
  __shared__ unsigned short s_h[WPB][16*68];   // [edge][j], pitch 68
  __shared__ float s_M[WPB][16*116];           // [edge][t]

  const int tid  = threadIdx.x;
  const int wid  = tid >> 6;
  const int lane = tid & 63;
  const int q    = lane >> 4;
  const int i    = lane & 15;

  for(int t=tid; t<NW3J; t+=TPB) s_w3j[t] = up.w3j[t];
  for(int t=tid; t<352; t+=TPB)  s_b2[t]  = b2[t];
  for(int t=tid; t<512; t+=TPB)  s_w1[t]  = w1[t];
  if(tid < 64) s_b1[tid] = b1[tid];
  __syncthreads();   // only barrier: shared weight staging

  const int nidx   = blockIdx.x*WPB + wid;
  const bool active = nidx < NN;
  const int node   = active ? nidx : 0;
  const int start  = offp[node];
  const int deg    = active ? (offp[node+1] - start) : 0;

  const float dpx = pos[node*3+0], dpy = pos[node*3+1], dpz = pos[node*3+2];

  float acc1[9], acc2[9];
  #pragma unroll
  for(int k=0;k<9;k++){ acc1[k]=0.f; acc2[k]=0.f; }

  char* hbytes = (char*)&s_h[wid][0];
  float* Mb = &s_M[wid][0];

  constexpr int PI_[11]   = {0,0,0,1,1,1,1,2,2,2,2};
  constexpr int PK_[11]   = {0,1,2,1,0,2,1,2,1,0,2};
  constexpr int TOFF_[11] = {0,1,4,9,18,21,36,45,70,85,90};
  constexpr int AO_[3]    = {0,1,4};

  const int nch = (deg + 15) >> 4;
  const uint4* w2f4 = (const uint4*)w2f;

  for(int ch=0; ch<nch; ch++){
    // ---- geometry for edge i (redundant across the 4 quads) ----
    int ei = ch*16 + i;
    bool v = ei < deg;
    int eg = v ? eid[start+ei] : 0;
    int se = v ? src[eg] : node;
    float px = pos[se*3+0]-dpx, py = pos[se*3+1]-dpy, pz = pos[se*3+2]-dpz;
    float d2 = px*px + py*py + pz*pz;
    float d  = v ? sqrtf(d2) : 1e9f;     // invalid edge -> cutoff 0
    float inv = 1.0f/fmaxf(d, 1e-12f);
    float x = px*inv, y = py*inv, z = pz*inv;
    float yv[9];
    yv[0]=1.0f;
    yv[1]=1.7320508075688772f*y;
    yv[2]=1.7320508075688772f*z;
    yv[3]=1.7320508075688772f*x;
    yv[4]=3.872983346207417f*x*y;
    yv[5]=3.872983346207417f*y*z;
    yv[6]=1.118033988749895f*(3.0f*z*z-1.0f);
    yv[7]=3.872983346207417f*x*z;
    yv[8]=1.9364916731037085f*(x*x-y*y);
    float bes[8];
    {
      float tt = d * 0.2f;
      float st = (tt > 0.0f) ? tt : 1.0f;
      float msk = (tt > 0.0f && tt < 1.0f) ? 1.0f : 0.0f;
      float ang = 3.14159265358979323846f * tt;
      float s1 = __sinf(ang), c1 = __cosf(ang);
      float kk2 = 0.6324555320336759f * msk / st;
      float c2 = 2.0f*c1;
      float sp = 0.0f, sc = s1;
      bes[0] = kk2*s1;
      #pragma unroll
      for(int n=1;n<8;n++){ float sn = c2*sc - sp; sp = sc; sc = sn; bes[n] = kk2*sn; }
    }
    float cut;
    {
      float uu = d*0.25f;
      float u2 = uu*uu;
      float u5 = u2*u2*uu;
      float env = 1.0f - 6.0f*u5 + 5.0f*u5*uu;
      cut = (d < 4.0f) ? env : 0.0f;
    }

    // ---- MLP1: lane (q,i) computes h[j], j = q*16+s, for edge i ----
    unsigned hp[8];
    #pragma unroll
    for(int s=0;s<16;s++){
      int j = q*16 + s;
      float a = s_b1[j];
      #pragma unroll
      for(int k=0;k<8;k++) a += bes[k]*s_w1[k*64+j];
      float sg = 1.0f/(1.0f + __expf(-a));
      float h = a*sg;
      unsigned ub = __float_as_uint(h);
      ub = (ub + 0x7fffu + ((ub>>16)&1u)) >> 16;   // RNE bf16
      if(s & 1) hp[s>>1] |= ub<<16; else hp[s>>1] = ub;
    }
    {
      uint2* wp = (uint2*)(hbytes + i*136 + q*32);
      wp[0] = make_uint2(hp[0],hp[1]);
      wp[1] = make_uint2(hp[2],hp[3]);
      wp[2] = make_uint2(hp[4],hp[5]);
      wp[3] = make_uint2(hp[6],hp[7]);
    }

    // ---- M[a,c](edge i): lane (q,i) builds entries t = q+4s ----
    for(int s5=0; s5<29; s5++){
      int t = q + 4*s5;
      if(t < NM){
        unsigned md = up.meta[t];
        int woff = md & 1023;
        int nc   = (md>>10) & 15;
        int nb   = (md>>14) & 15;
        int boff = (md>>18) & 15;
        float sm = 0.0f;
        for(int b=0;b<nb;b++) sm += s_w3j[woff + b*nc] * yv[boff + b];
        Mb[i*116 + t] = sm;
      }
    }
    // same-wave LDS ops are in-order: no barrier needed before reads below.

    // ---- A fragments: A[m=lane&15][k = 32*kk + q*8 + jj] ----
    union UA { uint2 u2[2]; bf16x8 v; };
    UA A0, A1;
    {
      const char* ab = hbytes + i*136 + q*16;
      A0.u2[0] = *(const uint2*)(ab);
      A0.u2[1] = *(const uint2*)(ab + 8);
      A1.u2[0] = *(const uint2*)(ab + 64);
      A1.u2[1] = *(const uint2*)(ab + 72);
    }

    // ---- two p-halves: MFMA radial tiles, then TP in C layout ----
    #pragma unroll
    for(int half=0; half<2; half++){
      const int p0 = (half==0) ? 0 : 6;
      const int p1 = (half==0) ? 6 : 11;
      const int t0 = 2*p0;
      const int NT = 2*(p1-p0);   // 12 or 10
      f32x4 C[12];
      #pragma unroll
      for(int tt=0; tt<12; tt++){
        if(tt < NT){
          int t = t0 + tt;
          union UB { uint4 u4; bf16x8 v; } B0, B1;
          B0.u4 = w2f4[(t*2+0)*64 + lane];
          B1.u4 = w2f4[(t*2+1)*64 + lane];
          f32x4 c = {0.f,0.f,0.f,0.f};
          c = __builtin_amdgcn_mfma_f32_16x16x32_bf16(A0.v, B0.v, c, 0,0,0);
          c = __builtin_amdgcn_mfma_f32_16x16x32_bf16(A1.v, B1.v, c, 0,0,0);
          C[tt] = c;
        }
      }
      // C row = edge (4q+reg), col = channel i (even tile) / i+16 (odd tile)
      #pragma unroll
      for(int r=0;r<4;r++){
        int e4 = q*4 + r;
        float cutv = __shfl(cut, e4);
        int   sv   = __shfl(se,  e4);
        const float* nr = nodes + (long)sv*288;
        float xv1[9], xv2[9];
        xv1[0] = nr[i];      xv2[0] = nr[i+16];
        #pragma unroll
        for(int c=0;c<3;c++){ xv1[1+c]=nr[32+i*3+c];  xv2[1+c]=nr[32+(i+16)*3+c]; }
        #pragma unroll
        for(int c=0;c<5;c++){ xv1[4+c]=nr[128+i*5+c]; xv2[4+c]=nr[128+(i+16)*5+c]; }
        const float* Me = Mb + e4*116;
        #pragma unroll
        for(int p=p0;p<p1;p++){
          int tt = 2*p - t0;
          float wr1 = (C[tt][r]   + s_b2[p*32+i])    * cutv;
          float wr2 = (C[tt+1][r] + s_b2[p*32+16+i]) * cutv;
          const int na = 2*PI_[p]+1, nc = 2*PK_[p]+1;
          const int ai = AO_[PI_[p]], ko = AO_[PK_[p]];
          #pragma unroll
          for(int a=0;a<na;a++){
            float x1 = xv1[ai+a]*wr1;
            float x2 = xv2[ai+a]*wr2;
            #pragma unroll
            for(int c=0;c<nc;c++){
              float Mv = Me[TOFF_[p] + a*nc + c];
              acc1[ko+c] += x1*Mv;
              acc2[ko+c] += x2*Mv;
            }
          }
        }
      }
    }
  }

  // reduce partial sums over the 4 quads
  #pragma unroll
  for(int k=0;k<9;k++){
    acc1[k] += __shfl_xor(acc1[k], 16);
    acc1[k] += __shfl_xor(acc1[k], 32);
    acc2[k] += __shfl_xor(acc2[k], 16);
    acc2[k] += __shfl_xor(acc2[k], 32);
  }

  if(active){
    float* ob = outp + (long)node*288;
    if(lane < 16){
      ob[i] = 0.2f*acc1[0];
      #pragma unroll
      for(int c=0;c<3;c++) ob[32 + i*3 + c] = 0.2f*acc1[1+c];
      #pragma unroll
      for(int c=0;c<5;c++) ob[128 + i*5 + c] = 0.2f*acc1[4+c];
    } else if(lane < 32){
      int u = i + 16;
      ob[u] = 0.2f*acc2[0];
      #pragma unroll
      for(int c=0;c<3;c++) ob[32 + u*3 + c] = 0.2f*acc2[1+c];
      #pragma unroll
      for(int c=0;c<5;c++) ob[128 + u*5 + c] = 0.2f*acc2[4+c];
    }
  }
}

// ---------------- launch ----------------------------------------------------

extern "C" void kernel_launch(void* const* d_in, const int* in_sizes, int n_in,
                              void* d_out, int out_size, void* d_ws, size_t ws_size,
                              hipStream_t stream) {
  const float* nodes = (const float*)d_in[0];
  const float* pos   = (const float*)d_in[1];
  const int* src = (const int*)d_in[2];
  const int* dst = (const int*)d_in[3];
  const float* w1 = (const float*)d_in[4];
  const float* b1 = (const float*)d_in[5];
  const float* w2 = (const float*)d_in[6];
  const float* b2 = (const float*)d_in[7];

  const int E  = in_sizes[2];
  const int NN = in_sizes[0] / 288;
  float* outp = (float*)d_out;

  int* counts = (int*)d_ws;                 // NN (zeroed)
  int* offp   = counts + NN;                // NN+1
  int* cursor = offp + NN + 1;              // NN
  int* eid    = cursor + NN;                // E
  unsigned short* w2f = (unsigned short*)(eid + E);  // 22528 bf16

  hipMemsetAsync(counts, 0, (size_t)NN*sizeof(int), stream);
  repack_w2f<<<(22528 + 255)/256, 256, 0, stream>>>(w2, w2f);
  count_kernel<<<(E+255)/256, 256, 0, stream>>>(dst, counts, E);
  scan_kernel<<<1, SCAN_T, 0, stream>>>(counts, offp, cursor, NN);
  edge_scatter_kernel<<<(E+255)/256, 256, 0, stream>>>(dst, cursor, eid, E);

  int nblocks = (NN + WPB - 1)/WPB;
  node_kernel<<<nblocks, TPB, 0, stream>>>(nodes, pos, src, offp, eid, w2f,
                                           w1, b1, b2, outp, NN, g_upload);
}

// Round 5
// 545.680 us; speedup vs baseline: 2.2075x; 2.2075x over previous
//
#include <hip/hip_runtime.h>
#include <hip/hip_bf16.h>
#include <cmath>
#include <complex>

#define TPB 256
#define SUBS 8
#define EPG 4
#define NM 115
#define NW3J 363
#define SCAN_T 1024
#define NBUCK 256
#define W2N (64*32*12)   // repacked w2 bf16 elements

// ---------------- host-side W3J construction (exact port of reference) ------
namespace {

double fct(int n){ double r=1; for(int i=2;i<=n;i++) r*=i; return r; }

double su2_cg(int j1,int j2,int j3,int m1,int m2,int m3){
  if(m1+m2!=m3) return 0.0;
  double pref = std::sqrt((2*j3+1)*fct(j1+j2-j3)*fct(j1-j2+j3)*fct(-j1+j2+j3)/fct(j1+j2+j3+1));
  pref *= std::sqrt(fct(j3+m3)*fct(j3-m3)*fct(j1-m1)*fct(j1+m1)*fct(j2-m2)*fct(j2+m2));
  double s=0;
  for(int k=0;k<=j1+j2-j3;k++){
    int d0=k, d1=j1+j2-j3-k, d2=j1-m1-k, d3=j2+m2-k, d4=j3-j2+m1+k, d5=j3-j1-m2+k;
    if(d0<0||d1<0||d2<0||d3<0||d4<0||d5<0) continue;
    double t = 1.0/(fct(d0)*fct(d1)*fct(d2)*fct(d3)*fct(d4)*fct(d5));
    s += (k&1)? -t : t;
  }
  return pref*s;
}

typedef std::complex<double> cd;

void qmat(int l, cd q[5][5]){
  for(int i=0;i<5;i++) for(int j=0;j<5;j++) q[i][j] = cd(0,0);
  const double is2 = 1.0/std::sqrt(2.0);
  for(int m=-l;m<0;m++){ q[l+m][l-m] = cd(is2,0); q[l+m][l+m] = cd(0,-is2); }
  q[l][l] = cd(1,0);
  for(int m=1;m<=l;m++){ double sg = (m&1)? -1.0: 1.0; q[l+m][l+m] = cd(sg*is2,0); q[l+m][l-m] = cd(0, sg*is2); }
  cd ph(1,0), mi(0,-1);
  for(int t=0;t<l;t++) ph *= mi;
  for(int i=0;i<5;i++) for(int j=0;j<5;j++) q[i][j] *= ph;
}

void w3j_calc(int l1,int l2,int l3,double* out){
  int n1=2*l1+1,n2=2*l2+1,n3=2*l3+1;
  double C[5][5][5] = {};
  for(int m1=-l1;m1<=l1;m1++)for(int m2=-l2;m2<=l2;m2++)for(int m3=-l3;m3<=l3;m3++)
    C[l1+m1][l2+m2][l3+m3] = su2_cg(l1,l2,l3,m1,m2,m3);
  cd q1[5][5], q2[5][5], q3[5][5];
  qmat(l1,q1); qmat(l2,q2); qmat(l3,q3);
  double wr[125], wi[125];
  double nr=0, ni=0;
  for(int a=0;a<n1;a++)for(int b=0;b<n2;b++)for(int c=0;c<n3;c++){
    cd s(0,0);
    for(int i=0;i<n1;i++)for(int k=0;k<n2;k++)for(int m=0;m<n3;m++)
      s += q1[i][a]*q2[k][b]*std::conj(q3[m][c])*C[i][k][m];
    int idx = (a*n2+b)*n3+c;
    wr[idx]=s.real(); wi[idx]=s.imag();
    nr += s.real()*s.real(); ni += s.imag()*s.imag();
  }
  bool useR = std::sqrt(nr) >= std::sqrt(ni);
  double nn = std::sqrt(useR? nr: ni);
  for(int q=0;q<n1*n2*n3;q++) out[q] = (useR? wr[q]: wi[q])/nn;
}

struct UploadArg {
  float w3j[NW3J];        // PATH_W premultiplied, dense per path
  unsigned int meta[NM];  // per M-entry: woff | nc<<10 | nb<<14 | boff<<18
};

UploadArg g_upload;

struct BuildInit {
  BuildInit(){
    const int P[11][3] = {{0,0,0},{0,1,1},{0,2,2},{1,0,1},{1,1,0},{1,1,2},
                          {1,2,1},{2,0,2},{2,1,1},{2,2,0},{2,2,2}};
    const int cnt[3] = {3,4,4};
    const int AO[3] = {0,1,4};
    int off = 0, t = 0;
    for(int p=0;p<11;p++){
      int i=P[p][0], j=P[p][1], k=P[p][2];
      int na=2*i+1, nb=2*j+1, nc=2*k+1;
      double W[125];
      w3j_calc(i,j,k,W);
      double pw = std::sqrt((2.0*k+1.0)/(double)cnt[k]);
      for(int q=0;q<na*nb*nc;q++) g_upload.w3j[off+q] = (float)(W[q]*pw);
      for(int a=0;a<na;a++)
        for(int c=0;c<nc;c++)
          g_upload.meta[t++] = (unsigned)((off + a*nb*nc + c) | (nc<<10) | (nb<<14) | (AO[j]<<18));
      off += na*nb*nc;
    }
  }
};
BuildInit g_build_init;

} // namespace

// ---------------- aux kernels -----------------------------------------------

// fused: degree count + w2 bf16 repack ([j][u][pp], pp<12, p=11 zero)
__global__ void count_repack_kernel(const int* __restrict__ dst, int* __restrict__ counts,
                                    const float* __restrict__ w2,
                                    unsigned short* __restrict__ w2b, int E){
  int i = blockIdx.x*blockDim.x + threadIdx.x;
  if(i < W2N){
    int pp = i % 12;
    int u  = (i/12) % 32;
    int j  = i / (12*32);
    unsigned short o = 0;
    if(pp < 11){
      unsigned ub = __float_as_uint(w2[j*352 + pp*32 + u]);
      ub = (ub + 0x7fffu + ((ub>>16)&1u)) >> 16;   // RNE to bf16
      o = (unsigned short)ub;
    }
    w2b[i] = o;
  }
  if(i < E) atomicAdd(&counts[dst[i]], 1);
}

// single block: exclusive scan of counts -> off/cursor, plus degree-histogram
// exclusive scan -> bcur (for degree bucketing)
__global__ __launch_bounds__(SCAN_T) void megascan_kernel(const int* __restrict__ counts,
                                                          int* __restrict__ off,
                                                          int* __restrict__ cursor,
                                                          int* __restrict__ bcur, int NN){
  __shared__ int part[SCAN_T];
  __shared__ int lh[NBUCK];
  int t = threadIdx.x;
  if(t < NBUCK) lh[t] = 0;
  __syncthreads();
  int C = (NN + SCAN_T - 1)/SCAN_T;
  int base = t*C;
  int lim = min(base+C, NN);
  int s = 0;
  for(int i=base;i<lim;i++){
    int c = counts[i];
    s += c;
    atomicAdd(&lh[min(c, NBUCK-1)], 1);
  }
  part[t] = s;
  __syncthreads();
  for(int d=1; d<SCAN_T; d<<=1){
    int v = (t>=d)? part[t-d] : 0;
    __syncthreads();
    part[t] += v;
    __syncthreads();
  }
  int run = part[t] - s;
  for(int i=base;i<lim;i++){ off[i]=run; cursor[i]=run; run += counts[i]; }
  if(t == SCAN_T-1) off[NN] = part[t];
  __syncthreads();
  if(t == 0){
    int r = 0;
    for(int b=0;b<NBUCK;b++){ bcur[b] = r; r += lh[b]; }
  }
}

// fused: node bucket-sort scatter + edge CSR scatter
__global__ void scatter_kernel(const int* __restrict__ dst, const int* __restrict__ counts,
                               int* __restrict__ cursor, int* __restrict__ bcur,
                               int* __restrict__ node_order, int* __restrict__ eid,
                               int NN, int E){
  int i = blockIdx.x*blockDim.x + threadIdx.x;
  if(i < NN){
    int p = atomicAdd(&bcur[min(counts[i], NBUCK-1)], 1);
    node_order[p] = i;
  }
  if(i < E){
    int p = atomicAdd(&cursor[dst[i]], 1);
    eid[p] = i;
  }
}

// ---------------- main node-owned kernel ------------------------------------

__device__ __forceinline__ void up2(unsigned w, float& lo, float& hi){
  lo = __uint_as_float(w << 16);
  hi = __uint_as_float(w & 0xffff0000u);
}

__global__ __launch_bounds__(TPB) void node_kernel(
    const float* __restrict__ nodes,
    const float* __restrict__ pos,
    const int* __restrict__ src,
    const int* __restrict__ node_order,
    const int* __restrict__ off,
    const int* __restrict__ eid,
    const unsigned short* __restrict__ w2b,
    const float* __restrict__ w1,
    const float* __restrict__ b1,
    const float* __restrict__ b2,
    float* __restrict__ outp,
    int NN,
    UploadArg up)
{
  __shared__ float s_w3j[NW3J];
  __shared__ float s_w1[512];
  __shared__ float s_b1[64];
  __shared__ unsigned short s_w2[W2N];      // 48 KB bf16 [j][u][12]
  __shared__ float s_y[SUBS][EPG][12];
  __shared__ float s_h[SUBS][64][EPG];
  __shared__ float s_M[SUBS][EPG][NM+1];

  const int tid = threadIdx.x;
  const int u = tid & 31;
  const int sub = tid >> 5;

  for(int t = tid; t < NW3J; t += TPB) s_w3j[t] = up.w3j[t];
  for(int t = tid; t < 512; t += TPB)  s_w1[t]  = w1[t];
  if(tid < 64) s_b1[tid] = b1[tid];
  {
    const uint4* g4 = (const uint4*)w2b;
    uint4* s4 = (uint4*)s_w2;
    #pragma unroll
    for(int t=0; t<12; t++) s4[tid + t*TPB] = g4[tid + t*TPB];
  }
  __syncthreads();   // ONLY barrier: one-time staging. Subgroups independent after.

  const int nidx = blockIdx.x*SUBS + sub;
  const bool active = nidx < NN;
  const int node = active ? node_order[nidx] : 0;
  const int start = off[node];
  const int deg = active ? (off[node+1] - start) : 0;

  // hoisted per-lane loop invariants
  float b2r[11];
  #pragma unroll
  for(int p=0;p<11;p++) b2r[p] = b2[p*32+u];
  const float dpx = pos[node*3+0], dpy = pos[node*3+1], dpz = pos[node*3+2];

  float accv[9];
  #pragma unroll
  for(int q=0;q<9;q++) accv[q] = 0.0f;

  constexpr int PI_[11]   = {0,0,0,1,1,1,1,2,2,2,2};
  constexpr int PK_[11]   = {0,1,2,1,0,2,1,2,1,0,2};
  constexpr int TOFF_[11] = {0,1,4,9,18,21,36,45,70,85,90};
  constexpr int AO_[3]    = {0,1,4};

  const int nch = (deg + EPG - 1)/EPG;

  for(int ch=0; ch<nch; ch++){
    float bes[EPG][8];
    float cut[EPG];
    int vsrc[EPG];
    bool valid[EPG];

    #pragma unroll
    for(int e=0;e<EPG;e++){
      int ei = ch*EPG + e;
      bool v = (ei < deg);
      valid[e] = v;
      int eg = v ? eid[start + ei] : 0;
      int se = v ? src[eg] : node;   // invalid -> zero displacement, masked bessel
      vsrc[e] = se;
      float px = pos[se*3+0] - dpx;
      float py = pos[se*3+1] - dpy;
      float pz = pos[se*3+2] - dpz;
      float d2 = px*px + py*py + pz*pz;
      float d = sqrtf(d2);
      float inv = 1.0f / fmaxf(d, 1e-12f);
      float x = px*inv, y = py*inv, z = pz*inv;
      float yv[9];
      yv[0] = 1.0f;
      yv[1] = 1.7320508075688772f*y;
      yv[2] = 1.7320508075688772f*z;
      yv[3] = 1.7320508075688772f*x;
      yv[4] = 3.872983346207417f*x*y;
      yv[5] = 3.872983346207417f*y*z;
      yv[6] = 1.118033988749895f*(3.0f*z*z - 1.0f);
      yv[7] = 3.872983346207417f*x*z;
      yv[8] = 1.9364916731037085f*(x*x - y*y);
      #pragma unroll
      for(int q=0;q<9;q++) s_y[sub][e][q] = yv[q];  // all lanes same value
      // bessel via sin recurrence
      float tt = d * 0.2f;
      float st = (tt > 0.0f) ? tt : 1.0f;
      float msk = (tt > 0.0f && tt < 1.0f) ? 1.0f : 0.0f;
      float ang = 3.14159265358979323846f * tt;
      float s1 = __sinf(ang), c1 = __cosf(ang);
      float kk = 0.6324555320336759f * msk / st;
      float c2 = 2.0f*c1;
      float sp = 0.0f, sc = s1;
      bes[e][0] = kk*s1;
      #pragma unroll
      for(int n=1;n<8;n++){ float sn = c2*sc - sp; sp = sc; sc = sn; bes[e][n] = kk*sn; }
      float uu = d*0.25f;
      float u2 = uu*uu;
      float u5 = u2*u2*uu;
      float env = 1.0f - 6.0f*u5 + 5.0f*u5*uu;
      cut[e] = (d < 4.0f) ? env : 0.0f;
    }

    // MLP1: lane u computes h[j] for j=u,u+32, all EPG edges -> s_h[sub][j][e]
    // (same-wave producer/consumer: no barrier needed, LDS ops are in-order)
    #pragma unroll
    for(int half=0; half<2; half++){
      int j = u + 32*half;
      float hb = s_b1[j];
      float hh[EPG];
      #pragma unroll
      for(int e=0;e<EPG;e++){
        float a = hb;
        #pragma unroll
        for(int k=0;k<8;k++) a += bes[e][k]*s_w1[k*64+j];
        float sg = 1.0f/(1.0f + __expf(-a));
        hh[e] = a*sg;
      }
      float4 hv; hv.x = hh[0]; hv.y = hh[1]; hv.z = hh[2]; hv.w = hh[3];
      *(float4*)(&s_h[sub][j][0]) = hv;
    }

    // M[a,c] = sum_b W3J[a,b,c]*y[b]  (same-wave, no barrier)
    #pragma unroll
    for(int w=0; w<4; w++){
      int t = u + 32*w;
      if(t < NM){
        unsigned int md = up.meta[t];
        int woff = md & 1023;
        int nc   = (md>>10) & 15;
        int nb   = (md>>14) & 15;
        int boff = (md>>18) & 15;
        #pragma unroll
        for(int e=0;e<EPG;e++){
          float s = 0.0f;
          for(int b=0;b<nb;b++) s += s_w3j[woff + b*nc] * s_y[sub][e][boff + b];
          s_M[sub][e][t] = s;
        }
      }
    }

    // MLP2: wacc[e][p] = sum_j h[e][j] * w2[j][p*32+u] — all operands in LDS
    float wacc[EPG][11];
    #pragma unroll
    for(int e=0;e<EPG;e++)
      #pragma unroll
      for(int p=0;p<11;p++) wacc[e][p] = 0.0f;
    for(int j=0;j<64;j++){
      float4 hv = *(const float4*)(&s_h[sub][j][0]);
      const unsigned short* wrow = &s_w2[(j*32+u)*12];
      uint2 wa = *(const uint2*)(wrow);
      uint2 wb = *(const uint2*)(wrow+4);
      uint2 wc = *(const uint2*)(wrow+8);
      float sw[12];
      up2(wa.x, sw[0], sw[1]);  up2(wa.y, sw[2], sw[3]);
      up2(wb.x, sw[4], sw[5]);  up2(wb.y, sw[6], sw[7]);
      up2(wc.x, sw[8], sw[9]);  up2(wc.y, sw[10], sw[11]);
      float hh[4]; hh[0]=hv.x; hh[1]=hv.y; hh[2]=hv.z; hh[3]=hv.w;
      #pragma unroll
      for(int e=0;e<EPG;e++)
        #pragma unroll
        for(int p=0;p<11;p++) wacc[e][p] += hh[e]*sw[p];
    }

    // Tensor product, accumulate into registers
    #pragma unroll
    for(int e=0;e<EPG;e++){
      if(!valid[e]) continue;
      const float* nr = nodes + (long)vsrc[e]*288;
      float xv[9];
      xv[0] = nr[u];
      #pragma unroll
      for(int c=0;c<3;c++) xv[1+c] = nr[32 + u*3 + c];
      #pragma unroll
      for(int c=0;c<5;c++) xv[4+c] = nr[128 + u*5 + c];
      float wr[11];
      #pragma unroll
      for(int p=0;p<11;p++) wr[p] = (wacc[e][p] + b2r[p]) * cut[e];
      const float* Me = &s_M[sub][e][0];
      #pragma unroll
      for(int p=0;p<11;p++){
        const int na = 2*PI_[p]+1;
        const int nc = 2*PK_[p]+1;
        const float wv = wr[p];
        #pragma unroll
        for(int a=0;a<na;a++){
          float xw = xv[AO_[PI_[p]]+a] * wv;
          #pragma unroll
          for(int c=0;c<nc;c++){
            accv[AO_[PK_[p]]+c] += xw * Me[TOFF_[p] + a*nc + c];
          }
        }
      }
    }
    // no trailing barrier: next iteration's LDS writes are same-wave ordered
  }

  if(active){
    float* ob = outp + (long)node*288;
    ob[u] = 0.2f*accv[0];
    #pragma unroll
    for(int c=0;c<3;c++) ob[32 + u*3 + c] = 0.2f*accv[1+c];
    #pragma unroll
    for(int c=0;c<5;c++) ob[128 + u*5 + c] = 0.2f*accv[4+c];
  }
}

// ---------------- launch ----------------------------------------------------

extern "C" void kernel_launch(void* const* d_in, const int* in_sizes, int n_in,
                              void* d_out, int out_size, void* d_ws, size_t ws_size,
                              hipStream_t stream) {
  const float* nodes = (const float*)d_in[0];
  const float* pos   = (const float*)d_in[1];
  const int* src = (const int*)d_in[2];
  const int* dst = (const int*)d_in[3];
  const float* w1 = (const float*)d_in[4];
  const float* b1 = (const float*)d_in[5];
  const float* w2 = (const float*)d_in[6];
  const float* b2 = (const float*)d_in[7];

  const int E  = in_sizes[2];
  const int NN = in_sizes[0] / 288;
  float* outp = (float*)d_out;

  // workspace layout: w2b first (16B-aligned), then ints
  unsigned short* w2b = (unsigned short*)d_ws;       // W2N bf16 (48 KB)
  int* counts     = (int*)(w2b + W2N);               // NN (zeroed)
  int* offp       = counts + NN;                     // NN+1
  int* cursor     = offp + NN + 1;                   // NN
  int* bcur       = cursor + NN;                     // NBUCK
  int* node_order = bcur + NBUCK;                    // NN
  int* eid        = node_order + NN;                 // E

  hipMemsetAsync(counts, 0, (size_t)NN*sizeof(int), stream);

  int g1 = (max(E, W2N) + 255)/256;
  count_repack_kernel<<<g1, 256, 0, stream>>>(dst, counts, w2, w2b, E);
  megascan_kernel<<<1, SCAN_T, 0, stream>>>(counts, offp, cursor, bcur, NN);
  int g2 = (max(E, NN) + 255)/256;
  scatter_kernel<<<g2, 256, 0, stream>>>(dst, counts, cursor, bcur, node_order, eid, NN, E);

  int nblocks = (NN + SUBS - 1)/SUBS;
  node_kernel<<<nblocks, TPB, 0, stream>>>(nodes, pos, src, node_order, offp, eid,
                                           w2b, w1, b1, b2, outp, NN, g_upload);
}